// Round 3
// baseline (9275.860 us; speedup 1.0000x reference)
//
#include <hip/hip_runtime.h>
#include <cmath>

// B=32, T=128, E=512, H=1024, 4H=4096
typedef __attribute__((ext_vector_type(8))) short short8;
typedef __attribute__((ext_vector_type(4))) float f32x4;

__device__ inline short bf16r(float x) {
  union { float f; unsigned u; } v; v.f = x;
  unsigned r = (v.u + 0x7fff + ((v.u >> 16) & 1)) >> 16;
  return (short)r;
}
__device__ inline float bf2f(short s) {
  union { unsigned u; float f; } v; v.u = ((unsigned)(unsigned short)s) << 16;
  return v.f;
}

// ---------- small prep kernels ----------
__global__ __launch_bounds__(256) void init2(const float* __restrict__ h0,
                                             const float* __restrict__ c0,
                                             short* __restrict__ h,
                                             float* __restrict__ c) {
  int idx = blockIdx.x * 256 + threadIdx.x;  // (b,u) row-major
  h[idx] = bf16r(h0[idx]);
  c[idx] = c0[idx];
}

__global__ __launch_bounds__(256) void finalize2(const short* __restrict__ h,
                                                 const float* __restrict__ c,
                                                 float* __restrict__ out) {
  int idx = blockIdx.x * 256 + threadIdx.x;
  out[idx] = bf2f(h[idx]);
  out[32768 + idx] = c[idx];
}

__global__ void zero_cnt(unsigned* __restrict__ c) {
  if (threadIdx.x < 8) c[threadIdx.x] = 0u;
}

// x (B,T,E) fp32 -> xb rows r=t*32+b, (4096,512) bf16
__global__ __launch_bounds__(256) void cast_x(const float* __restrict__ x,
                                              short* __restrict__ xb) {
  int idx = blockIdx.x * 256 + threadIdx.x;
  int e = idx & 511, t = (idx >> 9) & 127, b = idx >> 16;
  xb[(((t << 5) + b) << 9) + e] = bf16r(x[idx]);
}

// permuted biases: bp[l][n'] = b_l[(n'&3)*1024 + (n'>>2)]
__global__ __launch_bounds__(256) void bias_perm(const float* __restrict__ b1,
                                                 const float* __restrict__ b2,
                                                 const float* __restrict__ b3,
                                                 const float* __restrict__ b4,
                                                 float* __restrict__ bp) {
  int idx = blockIdx.x * 256 + threadIdx.x;  // 0..16383
  int l = idx >> 12, c = idx & 4095;
  const float* s = (l == 0) ? b1 : (l == 1) ? b2 : (l == 2) ? b3 : b4;
  bp[idx] = s[((c & 3) << 10) | (c >> 2)];
}

// in fp32 (R,C) -> out bf16 (C,R); GPERM: out-row n' = (c&1023)*4 + (c>>10)
template <bool GPERM>
__global__ __launch_bounds__(256) void transpose_cast(const float* __restrict__ in,
                                                      short* __restrict__ out,
                                                      int R, int C) {
  __shared__ float tile[32][33];
  int c0 = blockIdx.x * 32, r0 = blockIdx.y * 32;
  int x = threadIdx.x & 31, y = threadIdx.x >> 5;
#pragma unroll
  for (int i = 0; i < 4; ++i)
    tile[y + i * 8][x] = in[(size_t)(r0 + y + i * 8) * C + c0 + x];
  __syncthreads();
#pragma unroll
  for (int i = 0; i < 4; ++i) {
    int c = c0 + y + i * 8;
    int n = GPERM ? (((c & 1023) << 2) | (c >> 10)) : c;
    out[(size_t)n * R + r0 + x] = bf16r(tile[x][y + i * 8]);
  }
}

// ---------- bf16 MFMA GEMM ----------
// A (M,K) bf16 rm; Bt (N,K) bf16 rm; C = A·Bt^T + bias
// MODE 1: fp32 out xWp[t][col][b] ; MODE 2: bf16 rm + relu ; MODE 3: fp32, (B,T,E)
template <int MODE>
__global__ __launch_bounds__(256) void gemm_bf16(const short* __restrict__ A,
                                                 const short* __restrict__ Bt,
                                                 const float* __restrict__ bias,
                                                 void* __restrict__ Cout,
                                                 int M, int N, int K) {
  __shared__ short As[128 * 40];
  __shared__ short Bs[128 * 40];
  const int tid = threadIdx.x;
  const int lane = tid & 63, wave = tid >> 6;
  const int lrow = lane & 15, lk = lane >> 4;
  const int m0 = (wave >> 1) * 64, n0 = (wave & 1) * 64;
  const int r = tid & 127, half = tid >> 7;
  const int mbase = blockIdx.y * 128, nbase = blockIdx.x * 128;

  f32x4 acc[4][4] = {};

  const short* Ab = A + (size_t)(mbase + r) * K + half * 16;
  const short* Bb = Bt + (size_t)(nbase + r) * K + half * 16;
  short* AsW = As + r * 40 + half * 16;
  short* BsW = Bs + r * 40 + half * 16;

  for (int k0 = 0; k0 < K; k0 += 32) {
    short8 av0 = *(const short8*)(Ab + k0);
    short8 av1 = *(const short8*)(Ab + k0 + 8);
    short8 bv0 = *(const short8*)(Bb + k0);
    short8 bv1 = *(const short8*)(Bb + k0 + 8);
    __syncthreads();
    *(short8*)(AsW) = av0;
    *(short8*)(AsW + 8) = av1;
    *(short8*)(BsW) = bv0;
    *(short8*)(BsW + 8) = bv1;
    __syncthreads();
    short8 af[4], bfr[4];
#pragma unroll
    for (int i = 0; i < 4; ++i)
      af[i] = *(const short8*)(As + (m0 + i * 16 + lrow) * 40 + lk * 8);
#pragma unroll
    for (int i = 0; i < 4; ++i)
      bfr[i] = *(const short8*)(Bs + (n0 + i * 16 + lrow) * 40 + lk * 8);
#pragma unroll
    for (int i = 0; i < 4; ++i)
#pragma unroll
      for (int j = 0; j < 4; ++j)
        acc[i][j] = __builtin_amdgcn_mfma_f32_16x16x32_bf16(af[i], bfr[j],
                                                            acc[i][j], 0, 0, 0);
  }

#pragma unroll
  for (int i = 0; i < 4; ++i) {
    const int grow0 = mbase + m0 + i * 16 + lk * 4;
#pragma unroll
    for (int j = 0; j < 4; ++j) {
      const int gcol = nbase + n0 + j * 16 + lrow;
      const float bv = bias[gcol];
      f32x4 v = acc[i][j];
      if constexpr (MODE == 1) {
        int t = grow0 >> 5, b = grow0 & 31;
        f32x4 o;
        o[0] = v[0] + bv; o[1] = v[1] + bv; o[2] = v[2] + bv; o[3] = v[3] + bv;
        *(f32x4*)((float*)Cout + ((size_t)t * 4096 + gcol) * 32 + b) = o;
      } else if constexpr (MODE == 2) {
        short* o = (short*)Cout;
#pragma unroll
        for (int jj = 0; jj < 4; ++jj)
          o[(size_t)(grow0 + jj) * N + gcol] = bf16r(fmaxf(v[jj] + bv, 0.f));
      } else {
        float* o = (float*)Cout;
#pragma unroll
        for (int jj = 0; jj < 4; ++jj) {
          int rr = grow0 + jj;
          int orow = ((rr & 31) << 7) | (rr >> 5);
          o[(size_t)orow * N + gcol] = v[jj] + bv;
        }
      }
    }
  }
}

// ---------- persistent recurrent kernel (whole layer, 128 steps) ----------
// xWp (T,4096,32) fp32 fragment layout; Utp (4096,1024) bf16 gate-interleaved;
// hb0/hb1 (32,1024) bf16 double buffer (hb0 holds h_init; final h ends in hb0);
// cst (32,1024) fp32 (carried across layers); seq (T,32,1024) bf16 out.
// 128 blocks x 128 threads; block owns 32 cols; U slice in LDS (64KB, swizzled).
#define NBLK 128
__global__ __launch_bounds__(128) void lstm_persist(
    const float* __restrict__ xWp, const short* __restrict__ Utp,
    short* __restrict__ hb0, short* __restrict__ hb1, float* __restrict__ cst,
    short* __restrict__ seq, unsigned* __restrict__ cnt) {
  __shared__ short Us[32 * 1024];  // 64KB
  const int tid = threadIdx.x;
  const int lane = tid & 63, wave = tid >> 6;
  const int lrow = lane & 15, lk = lane >> 4;
  const int colg = blockIdx.x * 32 + wave * 16 + lrow;  // global n'
  const int coll = wave * 16 + lrow;                    // local col

  // stage U slice into LDS, XOR-swizzled (byte ^= (col&7)<<4)
  {
    const int c = tid >> 2, q = tid & 3;
    const short* src = Utp + (size_t)(blockIdx.x * 32 + c) * 1024 + q * 256;
    const int swz = (c & 7) << 4;
    char* base = (char*)Us + c * 2048;
#pragma unroll
    for (int j = 0; j < 32; ++j) {
      short8 v = *(const short8*)(src + j * 8);
      *(short8*)(base + (((q * 256 + j * 8) * 2) ^ swz)) = v;
    }
  }

  const int g = colg & 3, u = colg >> 2;
  float creg[2][4];
#pragma unroll
  for (int h = 0; h < 2; ++h)
#pragma unroll
    for (int jj = 0; jj < 4; ++jj)
      creg[h][jj] = cst[(h * 16 + lk * 4 + jj) * 1024 + u];

  const int swzr = (coll & 7) << 4;
  const char* Ubase = (const char*)Us + coll * 2048;
  __syncthreads();

  for (int t = 0; t < 128; ++t) {
    const short* hin = (t & 1) ? hb1 : hb0;
    short* hout = (t & 1) ? hb0 : hb1;
    const float* xb = xWp + ((size_t)t * 4096 + colg) * 32;
    f32x4 acc0 = *(const f32x4*)(xb + lk * 4);
    f32x4 acc1 = *(const f32x4*)(xb + 16 + lk * 4);
    const short* ha = hin + lrow * 1024 + lk * 8;
    const short* hbp = hin + (16 + lrow) * 1024 + lk * 8;
#pragma unroll 4
    for (int k0 = 0; k0 < 1024; k0 += 32) {
      short8 bfr = *(const short8*)(Ubase + ((k0 * 2 + lk * 16) ^ swzr));
      short8 a0 = *(const short8*)(ha + k0);
      short8 a1 = *(const short8*)(hbp + k0);
      acc0 = __builtin_amdgcn_mfma_f32_16x16x32_bf16(a0, bfr, acc0, 0, 0, 0);
      acc1 = __builtin_amdgcn_mfma_f32_16x16x32_bf16(a1, bfr, acc1, 0, 0, 0);
    }
#pragma unroll
    for (int h = 0; h < 2; ++h) {
#pragma unroll
      for (int jj = 0; jj < 4; ++jj) {
        float v = h ? acc1[jj] : acc0[jj];
        float zi = __shfl(v, (lane & ~3) | 0, 64);
        float zf = __shfl(v, (lane & ~3) | 1, 64);
        float zg = __shfl(v, (lane & ~3) | 2, 64);
        float zo = __shfl(v, (lane & ~3) | 3, 64);
        if (g == 0) {
          int b = h * 16 + lk * 4 + jj;
          float gi = 1.f / (1.f + expf(-zi));
          float gf = 1.f / (1.f + expf(-zf));
          float gg = fmaxf(zg, 0.f);
          float go = 1.f / (1.f + expf(-zo));
          float cn = gf * creg[h][jj] + gi * gg;
          creg[h][jj] = cn;
          short hv = bf16r(go * fmaxf(cn, 0.f));
          hout[b * 1024 + u] = hv;
          seq[(((size_t)t << 5) + b) * 1024 + u] = hv;
        }
      }
    }
    if (t != 127) {
      // grid barrier: release h-writes, acquire before next step's h-reads
      __syncthreads();
      if (tid == 0) {
        __hip_atomic_fetch_add(cnt, 1u, __ATOMIC_RELEASE,
                               __HIP_MEMORY_SCOPE_AGENT);
        const unsigned tgt = (unsigned)(t + 1) * NBLK;
        while (__hip_atomic_load(cnt, __ATOMIC_ACQUIRE,
                                 __HIP_MEMORY_SCOPE_AGENT) < tgt)
          __builtin_amdgcn_s_sleep(1);
      }
      __syncthreads();
    }
  }

  if (g == 0) {
#pragma unroll
    for (int h = 0; h < 2; ++h)
#pragma unroll
      for (int jj = 0; jj < 4; ++jj)
        cst[(h * 16 + lk * 4 + jj) * 1024 + u] = creg[h][jj];
  }
}

// ---------- launch ----------
extern "C" void kernel_launch(void* const* d_in, const int* in_sizes, int n_in,
                              void* d_out, int out_size, void* d_ws, size_t ws_size,
                              hipStream_t stream) {
  const float* x = (const float*)d_in[0];
  const float* h0 = (const float*)d_in[1];
  const float* c0 = (const float*)d_in[2];
  const float* W[4] = {(const float*)d_in[3], (const float*)d_in[6],
                       (const float*)d_in[9], (const float*)d_in[12]};
  const float* U[4] = {(const float*)d_in[4], (const float*)d_in[7],
                       (const float*)d_in[10], (const float*)d_in[13]};
  const float* bv[4] = {(const float*)d_in[5], (const float*)d_in[8],
                        (const float*)d_in[11], (const float*)d_in[14]};
  const float* Wd1 = (const float*)d_in[15];
  const float* bd1 = (const float*)d_in[16];
  const float* Wd2 = (const float*)d_in[17];
  const float* bd2 = (const float*)d_in[18];
  float* out = (float*)d_out;

  float* ws = (float*)d_ws;
  float* xWp = ws;                             // 16,777,216 f
  short* seq = (short*)(ws + 16777216);        // 4,194,304 bf16
  short* D1 = (short*)(ws + 18874368);         // 4,194,304 bf16
  short* Utp = (short*)(ws + 20971520);        // 4,194,304 bf16
  short* Wtp = (short*)(ws + 23068672);        // 4,194,304 bf16
  short* xb = (short*)(ws + 25165824);         // 2,097,152 bf16
  short* hA = (short*)(ws + 26214400);         // 32,768 bf16  (hb0)
  short* hB = (short*)(ws + 26230784);         // 32,768 bf16  (hb1)
  float* cst = ws + 26247168;                  // 32,768 f
  float* bp = ws + 26279936;                   // 16,384 f
  unsigned* cnt = (unsigned*)(ws + 26296320);  // 8 u32 barrier counters

  zero_cnt<<<1, 64, 0, stream>>>(cnt);
  init2<<<128, 256, 0, stream>>>(h0, c0, hA, cst);
  cast_x<<<8192, 256, 0, stream>>>(x, xb);
  bias_perm<<<64, 256, 0, stream>>>(bv[0], bv[1], bv[2], bv[3], bp);

  for (int l = 0; l < 4; ++l) {
    const int K = (l == 0) ? 512 : 1024;
    transpose_cast<true><<<dim3(128, 32), 256, 0, stream>>>(U[l], Utp, 1024, 4096);
    transpose_cast<true><<<dim3(128, K / 32), 256, 0, stream>>>(W[l], Wtp, K, 4096);
    const short* A = (l == 0) ? xb : seq;
    gemm_bf16<1><<<dim3(32, 32), 256, 0, stream>>>(A, Wtp, bp + l * 4096, xWp,
                                                   4096, 4096, K);
    lstm_persist<<<NBLK, 128, 0, stream>>>(xWp, Utp, hA, hB, cst, seq, cnt + l);
  }

  // dense head
  transpose_cast<false><<<dim3(32, 32), 256, 0, stream>>>(Wd1, Wtp, 1024, 1024);
  gemm_bf16<2><<<dim3(8, 32), 256, 0, stream>>>(seq, Wtp, bd1, D1, 4096, 1024, 1024);
  transpose_cast<false><<<dim3(16, 32), 256, 0, stream>>>(Wd2, Wtp, 1024, 512);
  gemm_bf16<3><<<dim3(4, 32), 256, 0, stream>>>(D1, Wtp, bd2, out, 4096, 512, 1024);

  finalize2<<<128, 256, 0, stream>>>(hA, cst, out + 2097152);
}

// Round 4
// 6530.311 us; speedup vs baseline: 1.4204x; 1.4204x over previous
//
#include <hip/hip_runtime.h>
#include <cmath>

// B=32, T=128, E=512, H=1024, 4H=4096
typedef __attribute__((ext_vector_type(8))) short short8;
typedef __attribute__((ext_vector_type(4))) float f32x4;
typedef unsigned long long u64;

__device__ inline short bf16r(float x) {
  union { float f; unsigned u; } v; v.f = x;
  unsigned r = (v.u + 0x7fff + ((v.u >> 16) & 1)) >> 16;
  return (short)r;
}
__device__ inline float bf2f(short s) {
  union { unsigned u; float f; } v; v.u = ((unsigned)(unsigned short)s) << 16;
  return v.f;
}
template <int CTRL>
__device__ inline float qb(float v) {  // quad_perm broadcast within lane-quads
  int i = __builtin_bit_cast(int, v);
  int r = __builtin_amdgcn_update_dpp(0, i, CTRL, 0xf, 0xf, true);
  return __builtin_bit_cast(float, r);
}

// ---------- small prep kernels ----------
__global__ __launch_bounds__(256) void init2(const float* __restrict__ h0,
                                             const float* __restrict__ c0,
                                             short* __restrict__ hseq0,
                                             float* __restrict__ c) {
  int idx = blockIdx.x * 256 + threadIdx.x;  // (b,u) row-major
  hseq0[idx] = bf16r(h0[idx]);
  c[idx] = c0[idx];
}

__global__ __launch_bounds__(256) void finalize2(const short* __restrict__ h,
                                                 const float* __restrict__ c,
                                                 float* __restrict__ out) {
  int idx = blockIdx.x * 256 + threadIdx.x;
  out[idx] = bf2f(h[idx]);
  out[32768 + idx] = c[idx];
}

__global__ void zero_cnt(unsigned* __restrict__ c) {
  if (threadIdx.x < 8) c[threadIdx.x] = 0u;
}

__global__ __launch_bounds__(256) void copy_h(const int* __restrict__ src,
                                              int* __restrict__ dst) {
  int i = blockIdx.x * 256 + threadIdx.x;  // 16384 ints = 64KB
  dst[i] = src[i];
}

// x (B,T,E) fp32 -> xb rows r=t*32+b, (4096,512) bf16
__global__ __launch_bounds__(256) void cast_x(const float* __restrict__ x,
                                              short* __restrict__ xb) {
  int idx = blockIdx.x * 256 + threadIdx.x;
  int e = idx & 511, t = (idx >> 9) & 127, b = idx >> 16;
  xb[(((t << 5) + b) << 9) + e] = bf16r(x[idx]);
}

// permuted biases: bp[l][n'] = b_l[(n'&3)*1024 + (n'>>2)]
__global__ __launch_bounds__(256) void bias_perm(const float* __restrict__ b1,
                                                 const float* __restrict__ b2,
                                                 const float* __restrict__ b3,
                                                 const float* __restrict__ b4,
                                                 float* __restrict__ bp) {
  int idx = blockIdx.x * 256 + threadIdx.x;  // 0..16383
  int l = idx >> 12, c = idx & 4095;
  const float* s = (l == 0) ? b1 : (l == 1) ? b2 : (l == 2) ? b3 : b4;
  bp[idx] = s[((c & 3) << 10) | (c >> 2)];
}

// in fp32 (R,C) -> out bf16 (C,R); GPERM: out-row n' = (c&1023)*4 + (c>>10)
template <bool GPERM>
__global__ __launch_bounds__(256) void transpose_cast(const float* __restrict__ in,
                                                      short* __restrict__ out,
                                                      int R, int C) {
  __shared__ float tile[32][33];
  int c0 = blockIdx.x * 32, r0 = blockIdx.y * 32;
  int x = threadIdx.x & 31, y = threadIdx.x >> 5;
#pragma unroll
  for (int i = 0; i < 4; ++i)
    tile[y + i * 8][x] = in[(size_t)(r0 + y + i * 8) * C + c0 + x];
  __syncthreads();
#pragma unroll
  for (int i = 0; i < 4; ++i) {
    int c = c0 + y + i * 8;
    int n = GPERM ? (((c & 1023) << 2) | (c >> 10)) : c;
    out[(size_t)n * R + r0 + x] = bf16r(tile[x][y + i * 8]);
  }
}

// ---------- bf16 MFMA GEMM ----------
// A (M,K) bf16 rm; Bt (N,K) bf16 rm; C = A·Bt^T + bias
// MODE 1: fp32 out xWp[t][col][b] ; MODE 2: bf16 rm + relu ; MODE 3: fp32, (B,T,E)
template <int MODE>
__global__ __launch_bounds__(256) void gemm_bf16(const short* __restrict__ A,
                                                 const short* __restrict__ Bt,
                                                 const float* __restrict__ bias,
                                                 void* __restrict__ Cout,
                                                 int M, int N, int K) {
  __shared__ short As[128 * 40];
  __shared__ short Bs[128 * 40];
  const int tid = threadIdx.x;
  const int lane = tid & 63, wave = tid >> 6;
  const int lrow = lane & 15, lk = lane >> 4;
  const int m0 = (wave >> 1) * 64, n0 = (wave & 1) * 64;
  const int r = tid & 127, half = tid >> 7;
  const int mbase = blockIdx.y * 128, nbase = blockIdx.x * 128;

  f32x4 acc[4][4] = {};

  const short* Ab = A + (size_t)(mbase + r) * K + half * 16;
  const short* Bb = Bt + (size_t)(nbase + r) * K + half * 16;
  short* AsW = As + r * 40 + half * 16;
  short* BsW = Bs + r * 40 + half * 16;

  for (int k0 = 0; k0 < K; k0 += 32) {
    short8 av0 = *(const short8*)(Ab + k0);
    short8 av1 = *(const short8*)(Ab + k0 + 8);
    short8 bv0 = *(const short8*)(Bb + k0);
    short8 bv1 = *(const short8*)(Bb + k0 + 8);
    __syncthreads();
    *(short8*)(AsW) = av0;
    *(short8*)(AsW + 8) = av1;
    *(short8*)(BsW) = bv0;
    *(short8*)(BsW + 8) = bv1;
    __syncthreads();
    short8 af[4], bfr[4];
#pragma unroll
    for (int i = 0; i < 4; ++i)
      af[i] = *(const short8*)(As + (m0 + i * 16 + lrow) * 40 + lk * 8);
#pragma unroll
    for (int i = 0; i < 4; ++i)
      bfr[i] = *(const short8*)(Bs + (n0 + i * 16 + lrow) * 40 + lk * 8);
#pragma unroll
    for (int i = 0; i < 4; ++i)
#pragma unroll
      for (int j = 0; j < 4; ++j)
        acc[i][j] = __builtin_amdgcn_mfma_f32_16x16x32_bf16(af[i], bfr[j],
                                                            acc[i][j], 0, 0, 0);
  }

#pragma unroll
  for (int i = 0; i < 4; ++i) {
    const int grow0 = mbase + m0 + i * 16 + lk * 4;
#pragma unroll
    for (int j = 0; j < 4; ++j) {
      const int gcol = nbase + n0 + j * 16 + lrow;
      const float bv = bias[gcol];
      f32x4 v = acc[i][j];
      if constexpr (MODE == 1) {
        int t = grow0 >> 5, b = grow0 & 31;
        f32x4 o;
        o[0] = v[0] + bv; o[1] = v[1] + bv; o[2] = v[2] + bv; o[3] = v[3] + bv;
        *(f32x4*)((float*)Cout + ((size_t)t * 4096 + gcol) * 32 + b) = o;
      } else if constexpr (MODE == 2) {
        short* o = (short*)Cout;
#pragma unroll
        for (int jj = 0; jj < 4; ++jj)
          o[(size_t)(grow0 + jj) * N + gcol] = bf16r(fmaxf(v[jj] + bv, 0.f));
      } else {
        float* o = (float*)Cout;
#pragma unroll
        for (int jj = 0; jj < 4; ++jj) {
          int rr = grow0 + jj;
          int orow = ((rr & 31) << 7) | (rr >> 5);
          o[(size_t)orow * N + gcol] = v[jj] + bv;
        }
      }
    }
  }
}

// ---------- persistent recurrent kernel (whole layer, 128 steps) ----------
// xWp (T,4096,32) fp32 fragment layout; Utp (4096,1024) bf16 gate-interleaved;
// seqX (129,32,1024) bf16: [0]=h_init, step t reads [t], writes [t+1];
// cst (32,1024) fp32 carried across layers.
// 64 blocks x 256 threads; block owns 64 cols; U slice 128KB LDS (swizzled).
// Sync: relaxed agent atomics only (h written via sc-flagged u64 atomic stores
// -> coherent point; each seqX line is write-once-read-once per dispatch).
#define PBLK 64
__global__ __launch_bounds__(256) void lstm_persist(
    const float* __restrict__ xWp, const short* __restrict__ Utp,
    short* __restrict__ seqX, float* __restrict__ cst,
    unsigned* __restrict__ cnt) {
  __shared__ short Us[64 * 1024];  // 128KB
  const int tid = threadIdx.x;
  const int lane = tid & 63, wave = tid >> 6;
  const int lrow = lane & 15, lk = lane >> 4;
  const int colg = blockIdx.x * 64 + wave * 16 + lrow;
  const int coll = wave * 16 + lrow;
  const int u0 = blockIdx.x * 16 + wave * 4;

  // stage U slice (64 cols x 1024 k), XOR-swizzled
  {
    const int c = tid >> 2, q = tid & 3;
    const short* src = Utp + (size_t)(blockIdx.x * 64 + c) * 1024 + q * 256;
    const int swz = (c & 7) << 4;
    char* base = (char*)Us + c * 2048;
#pragma unroll
    for (int j = 0; j < 32; ++j) {
      short8 v = *(const short8*)(src + j * 8);
      *(short8*)(base + (((q * 256 + j * 8) * 2) ^ swz)) = v;
    }
  }

  const int u = colg >> 2;
  float creg[2][4];
#pragma unroll
  for (int h = 0; h < 2; ++h)
#pragma unroll
    for (int jj = 0; jj < 4; ++jj)
      creg[h][jj] = cst[(h * 16 + lk * 4 + jj) * 1024 + u];

  const int swzr = (coll & 7) << 4;
  const char* Ubase = (const char*)Us + coll * 2048;
  __syncthreads();

  f32x4 cur0, cur1;
  {
    const float* xb = xWp + (size_t)colg * 32;
    cur0 = *(const f32x4*)(xb + lk * 4);
    cur1 = *(const f32x4*)(xb + 16 + lk * 4);
  }

  for (int t = 0; t < 128; ++t) {
    const short* hin = seqX + t * 32768;
    short* hnx = seqX + (t + 1) * 32768;
    f32x4 acc0 = cur0, acc1 = cur1;
    const short* ha = hin + lrow * 1024 + lk * 8;
    const short* hbp = hin + (16 + lrow) * 1024 + lk * 8;
#pragma unroll 4
    for (int k0 = 0; k0 < 1024; k0 += 32) {
      short8 bfr = *(const short8*)(Ubase + ((k0 * 2 + lk * 16) ^ swzr));
      short8 a0 = *(const short8*)(ha + k0);
      short8 a1 = *(const short8*)(hbp + k0);
      acc0 = __builtin_amdgcn_mfma_f32_16x16x32_bf16(a0, bfr, acc0, 0, 0, 0);
      acc1 = __builtin_amdgcn_mfma_f32_16x16x32_bf16(a1, bfr, acc1, 0, 0, 0);
    }

    // gates: every lane of a quad computes its quad's (u) values via DPP bcast
    unsigned short hv[2][4];
#pragma unroll
    for (int h = 0; h < 2; ++h) {
#pragma unroll
      for (int jj = 0; jj < 4; ++jj) {
        float v = h ? acc1[jj] : acc0[jj];
        float zi = qb<0x00>(v);
        float zf = qb<0x55>(v);
        float zg = qb<0xAA>(v);
        float zo = qb<0xFF>(v);
        float gi = 1.f / (1.f + expf(-zi));
        float gf = 1.f / (1.f + expf(-zf));
        float gg = fmaxf(zg, 0.f);
        float go = 1.f / (1.f + expf(-zo));
        float cn = gf * creg[h][jj] + gi * gg;
        creg[h][jj] = cn;
        hv[h][jj] = (unsigned short)bf16r(go * fmaxf(cn, 0.f));
      }
    }
    // pack 4 consecutive u (from lanes lrow 0,4,8,12) into u64, store coherent
#pragma unroll
    for (int h = 0; h < 2; ++h) {
#pragma unroll
      for (int jj = 0; jj < 4; ++jj) {
        int vv = hv[h][jj];
        int w0 = __shfl(vv, (lane & 48) | 0, 64);
        int w1 = __shfl(vv, (lane & 48) | 4, 64);
        int w2 = __shfl(vv, (lane & 48) | 8, 64);
        int w3 = __shfl(vv, (lane & 48) | 12, 64);
        if (lrow == 0) {
          u64 pk = (u64)(unsigned)((w0 & 0xffff) | (w1 << 16)) |
                   ((u64)(unsigned)((w2 & 0xffff) | (w3 << 16)) << 32);
          int b = h * 16 + lk * 4 + jj;
          __hip_atomic_store((u64*)(hnx + b * 1024 + u0), pk, __ATOMIC_RELAXED,
                             __HIP_MEMORY_SCOPE_AGENT);
        }
      }
    }

    if (t != 127) {
      asm volatile("s_waitcnt vmcnt(0)" ::: "memory");  // h at coherent point
      // prefetch next step's xW during the barrier wait
      const float* xb = xWp + ((size_t)(t + 1) * 4096 + colg) * 32;
      cur0 = *(const f32x4*)(xb + lk * 4);
      cur1 = *(const f32x4*)(xb + 16 + lk * 4);
      __syncthreads();
      if (tid == 0) {
        __hip_atomic_fetch_add(cnt, 1u, __ATOMIC_RELAXED,
                               __HIP_MEMORY_SCOPE_AGENT);
        const unsigned tgt = (unsigned)(t + 1) * PBLK;
        while (__hip_atomic_load(cnt, __ATOMIC_RELAXED,
                                 __HIP_MEMORY_SCOPE_AGENT) < tgt)
          __builtin_amdgcn_s_sleep(1);
      }
      __syncthreads();
      asm volatile("" ::: "memory");
    }
  }

  if ((lrow & 3) == 0) {
#pragma unroll
    for (int h = 0; h < 2; ++h)
#pragma unroll
      for (int jj = 0; jj < 4; ++jj)
        cst[(h * 16 + lk * 4 + jj) * 1024 + u] = creg[h][jj];
  }
}

// ---------- launch ----------
extern "C" void kernel_launch(void* const* d_in, const int* in_sizes, int n_in,
                              void* d_out, int out_size, void* d_ws, size_t ws_size,
                              hipStream_t stream) {
  const float* x = (const float*)d_in[0];
  const float* h0 = (const float*)d_in[1];
  const float* c0 = (const float*)d_in[2];
  const float* W[4] = {(const float*)d_in[3], (const float*)d_in[6],
                       (const float*)d_in[9], (const float*)d_in[12]};
  const float* U[4] = {(const float*)d_in[4], (const float*)d_in[7],
                       (const float*)d_in[10], (const float*)d_in[13]};
  const float* bv[4] = {(const float*)d_in[5], (const float*)d_in[8],
                        (const float*)d_in[11], (const float*)d_in[14]};
  const float* Wd1 = (const float*)d_in[15];
  const float* bd1 = (const float*)d_in[16];
  const float* Wd2 = (const float*)d_in[17];
  const float* bd2 = (const float*)d_in[18];
  float* out = (float*)d_out;

  float* ws = (float*)d_ws;
  float* xWp = ws;                               // 16,777,216 f
  short* seqX = (short*)(ws + 16777216);         // 129*32768 bf16 (2,113,536 f)
  short* D1 = (short*)(ws + 18890752);           // 4,194,304 bf16
  short* Utp = (short*)(ws + 20987904);          // 4,194,304 bf16
  short* Wtp = (short*)(ws + 23085056);          // 4,194,304 bf16
  short* xb = (short*)(ws + 25182208);           // 2,097,152 bf16
  float* cst = ws + 26230784;                    // 32,768 f
  float* bp = ws + 26263552;                     // 16,384 f
  unsigned* cnt = (unsigned*)(ws + 26279936);    // 8 u32

  zero_cnt<<<1, 64, 0, stream>>>(cnt);
  init2<<<128, 256, 0, stream>>>(h0, c0, seqX, cst);
  cast_x<<<8192, 256, 0, stream>>>(x, xb);
  bias_perm<<<64, 256, 0, stream>>>(bv[0], bv[1], bv[2], bv[3], bp);

  for (int l = 0; l < 4; ++l) {
    const int K = (l == 0) ? 512 : 1024;
    transpose_cast<true><<<dim3(128, 32), 256, 0, stream>>>(U[l], Utp, 1024, 4096);
    transpose_cast<true><<<dim3(128, K / 32), 256, 0, stream>>>(W[l], Wtp, K, 4096);
    const short* A = (l == 0) ? xb : seqX + 32768;
    gemm_bf16<1><<<dim3(32, 32), 256, 0, stream>>>(A, Wtp, bp + l * 4096, xWp,
                                                   4096, 4096, K);
    if (l) copy_h<<<64, 256, 0, stream>>>((const int*)(seqX + 128 * 32768),
                                          (int*)seqX);
    lstm_persist<<<PBLK, 256, 0, stream>>>(xWp, Utp, seqX, cst, cnt + l);
  }

  // dense head
  transpose_cast<false><<<dim3(32, 32), 256, 0, stream>>>(Wd1, Wtp, 1024, 1024);
  gemm_bf16<2><<<dim3(8, 32), 256, 0, stream>>>(seqX + 32768, Wtp, bd1, D1, 4096,
                                                1024, 1024);
  transpose_cast<false><<<dim3(16, 32), 256, 0, stream>>>(Wd2, Wtp, 1024, 512);
  gemm_bf16<3><<<dim3(4, 32), 256, 0, stream>>>(D1, Wtp, bd2, out, 4096, 512, 1024);

  finalize2<<<128, 256, 0, stream>>>(seqX + 128 * 32768, cst, out + 2097152);
}

// Round 5
// 2960.524 us; speedup vs baseline: 3.1332x; 2.2058x over previous
//
#include <hip/hip_runtime.h>
#include <cmath>

// B=32, T=128, E=512, H=1024, 4H=4096
typedef __attribute__((ext_vector_type(8))) short short8;
typedef __attribute__((ext_vector_type(4))) float f32x4;
typedef unsigned long long u64;

__device__ inline short bf16r(float x) {
  union { float f; unsigned u; } v; v.f = x;
  unsigned r = (v.u + 0x7fff + ((v.u >> 16) & 1)) >> 16;
  return (short)r;
}
__device__ inline float bf2f(short s) {
  union { unsigned u; float f; } v; v.u = ((unsigned)(unsigned short)s) << 16;
  return v.f;
}
template <int CTRL>
__device__ inline float qb(float v) {  // quad_perm broadcast within lane-quads
  int i = __builtin_bit_cast(int, v);
  int r = __builtin_amdgcn_update_dpp(0, i, CTRL, 0xf, 0xf, true);
  return __builtin_bit_cast(float, r);
}

// ---------- small prep kernels ----------
__global__ __launch_bounds__(256) void init2(const float* __restrict__ h0,
                                             const float* __restrict__ c0,
                                             short* __restrict__ hseq0,
                                             float* __restrict__ c) {
  int idx = blockIdx.x * 256 + threadIdx.x;  // (b,u) row-major
  hseq0[idx] = bf16r(h0[idx]);
  c[idx] = c0[idx];
}

__global__ __launch_bounds__(256) void finalize2(const short* __restrict__ h,
                                                 const float* __restrict__ c,
                                                 float* __restrict__ out) {
  int idx = blockIdx.x * 256 + threadIdx.x;
  out[idx] = bf2f(h[idx]);
  out[32768 + idx] = c[idx];
}

__global__ __launch_bounds__(256) void zero_cnt(unsigned* __restrict__ c) {
  c[blockIdx.x * 256 + threadIdx.x] = 0u;  // 4 blocks -> 1024 u32
}

__global__ __launch_bounds__(256) void copy_h(const int* __restrict__ src,
                                              int* __restrict__ dst) {
  int i = blockIdx.x * 256 + threadIdx.x;  // 16384 ints = 64KB
  dst[i] = src[i];
}

// x (B,T,E) fp32 -> xb rows r=t*32+b, (4096,512) bf16
__global__ __launch_bounds__(256) void cast_x(const float* __restrict__ x,
                                              short* __restrict__ xb) {
  int idx = blockIdx.x * 256 + threadIdx.x;
  int e = idx & 511, t = (idx >> 9) & 127, b = idx >> 16;
  xb[(((t << 5) + b) << 9) + e] = bf16r(x[idx]);
}

// permuted biases: bp[l][n'] = b_l[(n'&3)*1024 + (n'>>2)]
__global__ __launch_bounds__(256) void bias_perm(const float* __restrict__ b1,
                                                 const float* __restrict__ b2,
                                                 const float* __restrict__ b3,
                                                 const float* __restrict__ b4,
                                                 float* __restrict__ bp) {
  int idx = blockIdx.x * 256 + threadIdx.x;  // 0..16383
  int l = idx >> 12, c = idx & 4095;
  const float* s = (l == 0) ? b1 : (l == 1) ? b2 : (l == 2) ? b3 : b4;
  bp[idx] = s[((c & 3) << 10) | (c >> 2)];
}

// in fp32 (R,C) -> out bf16 (C,R); GPERM: out-row n' = (c&1023)*4 + (c>>10)
template <bool GPERM>
__global__ __launch_bounds__(256) void transpose_cast(const float* __restrict__ in,
                                                      short* __restrict__ out,
                                                      int R, int C) {
  __shared__ float tile[32][33];
  int c0 = blockIdx.x * 32, r0 = blockIdx.y * 32;
  int x = threadIdx.x & 31, y = threadIdx.x >> 5;
#pragma unroll
  for (int i = 0; i < 4; ++i)
    tile[y + i * 8][x] = in[(size_t)(r0 + y + i * 8) * C + c0 + x];
  __syncthreads();
#pragma unroll
  for (int i = 0; i < 4; ++i) {
    int c = c0 + y + i * 8;
    int n = GPERM ? (((c & 1023) << 2) | (c >> 10)) : c;
    out[(size_t)n * R + r0 + x] = bf16r(tile[x][y + i * 8]);
  }
}

// ---------- bf16 MFMA GEMM ----------
// A (M,K) bf16 rm; Bt (N,K) bf16 rm; C = A·Bt^T + bias
// MODE 1: fp32 out xWp[t][col][b] ; MODE 2: bf16 rm + relu ; MODE 3: fp32, (B,T,E)
template <int MODE>
__global__ __launch_bounds__(256) void gemm_bf16(const short* __restrict__ A,
                                                 const short* __restrict__ Bt,
                                                 const float* __restrict__ bias,
                                                 void* __restrict__ Cout,
                                                 int M, int N, int K) {
  __shared__ short As[128 * 40];
  __shared__ short Bs[128 * 40];
  const int tid = threadIdx.x;
  const int lane = tid & 63, wave = tid >> 6;
  const int lrow = lane & 15, lk = lane >> 4;
  const int m0 = (wave >> 1) * 64, n0 = (wave & 1) * 64;
  const int r = tid & 127, half = tid >> 7;
  const int mbase = blockIdx.y * 128, nbase = blockIdx.x * 128;

  f32x4 acc[4][4] = {};

  const short* Ab = A + (size_t)(mbase + r) * K + half * 16;
  const short* Bb = Bt + (size_t)(nbase + r) * K + half * 16;
  short* AsW = As + r * 40 + half * 16;
  short* BsW = Bs + r * 40 + half * 16;

  for (int k0 = 0; k0 < K; k0 += 32) {
    short8 av0 = *(const short8*)(Ab + k0);
    short8 av1 = *(const short8*)(Ab + k0 + 8);
    short8 bv0 = *(const short8*)(Bb + k0);
    short8 bv1 = *(const short8*)(Bb + k0 + 8);
    __syncthreads();
    *(short8*)(AsW) = av0;
    *(short8*)(AsW + 8) = av1;
    *(short8*)(BsW) = bv0;
    *(short8*)(BsW + 8) = bv1;
    __syncthreads();
    short8 af[4], bfr[4];
#pragma unroll
    for (int i = 0; i < 4; ++i)
      af[i] = *(const short8*)(As + (m0 + i * 16 + lrow) * 40 + lk * 8);
#pragma unroll
    for (int i = 0; i < 4; ++i)
      bfr[i] = *(const short8*)(Bs + (n0 + i * 16 + lrow) * 40 + lk * 8);
#pragma unroll
    for (int i = 0; i < 4; ++i)
#pragma unroll
      for (int j = 0; j < 4; ++j)
        acc[i][j] = __builtin_amdgcn_mfma_f32_16x16x32_bf16(af[i], bfr[j],
                                                            acc[i][j], 0, 0, 0);
  }

#pragma unroll
  for (int i = 0; i < 4; ++i) {
    const int grow0 = mbase + m0 + i * 16 + lk * 4;
#pragma unroll
    for (int j = 0; j < 4; ++j) {
      const int gcol = nbase + n0 + j * 16 + lrow;
      const float bv = bias[gcol];
      f32x4 v = acc[i][j];
      if constexpr (MODE == 1) {
        int t = grow0 >> 5, b = grow0 & 31;
        f32x4 o;
        o[0] = v[0] + bv; o[1] = v[1] + bv; o[2] = v[2] + bv; o[3] = v[3] + bv;
        *(f32x4*)((float*)Cout + ((size_t)t * 4096 + gcol) * 32 + b) = o;
      } else if constexpr (MODE == 2) {
        short* o = (short*)Cout;
#pragma unroll
        for (int jj = 0; jj < 4; ++jj)
          o[(size_t)(grow0 + jj) * N + gcol] = bf16r(fmaxf(v[jj] + bv, 0.f));
      } else {
        float* o = (float*)Cout;
#pragma unroll
        for (int jj = 0; jj < 4; ++jj) {
          int rr = grow0 + jj;
          int orow = ((rr & 31) << 7) | (rr >> 5);
          o[(size_t)orow * N + gcol] = v[jj] + bv;
        }
      }
    }
  }
}

// ---------- persistent recurrent kernel (whole layer, 128 steps) ----------
// xWp (T,4096,32) fp32 fragment layout; Utp (4096,1024) bf16 gate-interleaved;
// seqX (129,32,1024) bf16: [0]=h_init, step t reads [t], writes [t+1];
// cst (32,1024) fp32 carried across layers.
// 64 blocks x 256 threads. U fragment in REGISTERS (32 x short8 / lane).
// h_t staged per step into LDS (64KB) via global_load_lds w/ pre-swizzled src.
// Barrier: distributed epoch slots (arr[b*16]), wave0 polls all 64.
#define PBLK 64
__global__ __launch_bounds__(256) void lstm_persist(
    const float* __restrict__ xWp, const short* __restrict__ Utp,
    short* __restrict__ seqX, float* __restrict__ cst,
    unsigned* __restrict__ arr, int ebase) {
  __shared__ short Hs[32768];  // 64KB: h_t [32 rows][1024 k], XOR-swizzled
  const int tid = threadIdx.x;
  const int lane = tid & 63, wave = tid >> 6;
  const int lrow = lane & 15, lk = lane >> 4;
  const int colg = blockIdx.x * 64 + wave * 16 + lrow;  // gate-interleaved n'
  const int u0 = blockIdx.x * 16 + wave * 4;
  const int u = colg >> 2;

  // U fragment -> registers (fully static indexing)
  short8 ureg[32];
  {
    const short* Ub = Utp + (size_t)colg * 1024 + lk * 8;
#pragma unroll
    for (int j = 0; j < 32; ++j) ureg[j] = *(const short8*)(Ub + j * 32);
  }

  float creg[2][4];
#pragma unroll
  for (int h = 0; h < 2; ++h)
#pragma unroll
    for (int jj = 0; jj < 4; ++jj)
      creg[h][jj] = cst[(h * 16 + lk * 4 + jj) * 1024 + u];

  // per-thread pre-swizzled global source offsets for h staging
  // LDS flat dest = j*4096 + wave*1024 + lane*16 ; row = dest>>11, col = dest&2047
  // src byte = row*2048 + (col ^ ((row&7)<<4))   (XOR involution)
  unsigned soff[16];
  {
    const int shi = wave >> 1, slo = wave & 1;
#pragma unroll
    for (int j = 0; j < 16; ++j) {
      int row = j * 2 + shi;
      unsigned col = (unsigned)(slo * 1024 + lane * 16);
      soff[j] = (unsigned)(row * 2048) + (col ^ ((unsigned)(row & 7) << 4));
    }
  }

  const unsigned swz = (unsigned)((lrow & 7) << 4);
  const char* hrd0 = (const char*)Hs + lrow * 2048;
  const char* hrd1 = (const char*)Hs + (lrow + 16) * 2048;

  for (int t = 0; t < 128; ++t) {
    // acc init from xW (issued early; drained by the staging barrier)
    const float* xb = xWp + ((size_t)t * 4096 + colg) * 32;
    f32x4 acc0 = *(const f32x4*)(xb + lk * 4);
    f32x4 acc1 = *(const f32x4*)(xb + 16 + lk * 4);

    // stage h_t into LDS (async, direct-to-LDS)
    const char* hsrc = (const char*)(seqX + (size_t)t * 32768);
#pragma unroll
    for (int j = 0; j < 16; ++j)
      __builtin_amdgcn_global_load_lds(
          (const __attribute__((address_space(1))) void*)(hsrc + soff[j]),
          (__attribute__((address_space(3))) void*)((char*)Hs + wave * 1024 +
                                                    j * 4096),
          16, 0, 0);
    __syncthreads();  // implies s_waitcnt vmcnt(0) lgkmcnt(0)

    // MFMA: 32 k-chunks, U from regs, h from LDS (swizzled ds_read_b128)
#pragma unroll
    for (int j = 0; j < 32; ++j) {
      unsigned off = ((unsigned)(j * 64 + lk * 16)) ^ swz;
      short8 a0 = *(const short8*)(hrd0 + off);
      short8 a1 = *(const short8*)(hrd1 + off);
      acc0 = __builtin_amdgcn_mfma_f32_16x16x32_bf16(a0, ureg[j], acc0, 0, 0, 0);
      acc1 = __builtin_amdgcn_mfma_f32_16x16x32_bf16(a1, ureg[j], acc1, 0, 0, 0);
    }

    // gates via DPP quad broadcast (all lanes of a quad compute their unit)
    unsigned short hv[2][4];
#pragma unroll
    for (int h = 0; h < 2; ++h) {
#pragma unroll
      for (int jj = 0; jj < 4; ++jj) {
        float v = h ? acc1[jj] : acc0[jj];
        float zi = qb<0x00>(v);
        float zf = qb<0x55>(v);
        float zg = qb<0xAA>(v);
        float zo = qb<0xFF>(v);
        float gi = 1.f / (1.f + expf(-zi));
        float gf = 1.f / (1.f + expf(-zf));
        float gg = fmaxf(zg, 0.f);
        float go = 1.f / (1.f + expf(-zo));
        float cn = gf * creg[h][jj] + gi * gg;
        creg[h][jj] = cn;
        hv[h][jj] = (unsigned short)bf16r(go * fmaxf(cn, 0.f));
      }
    }

    // pack 4 units (lanes lrow 0,4,8,12) -> u64, coherent store to seqX[t+1]
    short* hnx = seqX + (size_t)(t + 1) * 32768;
#pragma unroll
    for (int h = 0; h < 2; ++h) {
#pragma unroll
      for (int jj = 0; jj < 4; ++jj) {
        int vv = hv[h][jj];
        int w0 = __shfl(vv, (lane & 48) | 0, 64);
        int w1 = __shfl(vv, (lane & 48) | 4, 64);
        int w2 = __shfl(vv, (lane & 48) | 8, 64);
        int w3 = __shfl(vv, (lane & 48) | 12, 64);
        if (lrow == 0) {
          u64 pk = (u64)(unsigned)((w0 & 0xffff) | (w1 << 16)) |
                   ((u64)(unsigned)((w2 & 0xffff) | (w3 << 16)) << 32);
          int b = h * 16 + lk * 4 + jj;
          __hip_atomic_store((u64*)(hnx + b * 1024 + u0), pk, __ATOMIC_RELAXED,
                             __HIP_MEMORY_SCOPE_AGENT);
        }
      }
    }

    if (t != 127) {
      __syncthreads();  // drains this block's h stores (vmcnt(0) before barrier)
      const unsigned ep = (unsigned)(ebase + t + 1);
      if (tid == 0)
        __hip_atomic_store(arr + blockIdx.x * 16, ep, __ATOMIC_RELAXED,
                           __HIP_MEMORY_SCOPE_AGENT);
      if (tid < PBLK) {
        while (__hip_atomic_load(arr + tid * 16, __ATOMIC_RELAXED,
                                 __HIP_MEMORY_SCOPE_AGENT) < ep)
          __builtin_amdgcn_s_sleep(1);
      }
      __syncthreads();
    }
  }

  if ((lrow & 3) == 0) {
#pragma unroll
    for (int h = 0; h < 2; ++h)
#pragma unroll
      for (int jj = 0; jj < 4; ++jj)
        cst[(h * 16 + lk * 4 + jj) * 1024 + u] = creg[h][jj];
  }
}

// ---------- launch ----------
extern "C" void kernel_launch(void* const* d_in, const int* in_sizes, int n_in,
                              void* d_out, int out_size, void* d_ws, size_t ws_size,
                              hipStream_t stream) {
  const float* x = (const float*)d_in[0];
  const float* h0 = (const float*)d_in[1];
  const float* c0 = (const float*)d_in[2];
  const float* W[4] = {(const float*)d_in[3], (const float*)d_in[6],
                       (const float*)d_in[9], (const float*)d_in[12]};
  const float* U[4] = {(const float*)d_in[4], (const float*)d_in[7],
                       (const float*)d_in[10], (const float*)d_in[13]};
  const float* bv[4] = {(const float*)d_in[5], (const float*)d_in[8],
                        (const float*)d_in[11], (const float*)d_in[14]};
  const float* Wd1 = (const float*)d_in[15];
  const float* bd1 = (const float*)d_in[16];
  const float* Wd2 = (const float*)d_in[17];
  const float* bd2 = (const float*)d_in[18];
  float* out = (float*)d_out;

  float* ws = (float*)d_ws;
  float* xWp = ws;                               // 16,777,216 f
  short* seqX = (short*)(ws + 16777216);         // 129*32768 bf16 (2,113,536 f)
  short* D1 = (short*)(ws + 18890752);           // 4,194,304 bf16
  short* Utp = (short*)(ws + 20987904);          // 4,194,304 bf16
  short* Wtp = (short*)(ws + 23085056);          // 4,194,304 bf16
  short* xb = (short*)(ws + 25182208);           // 2,097,152 bf16
  float* cst = ws + 26230784;                    // 32,768 f
  float* bp = ws + 26263552;                     // 16,384 f
  unsigned* arr = (unsigned*)(ws + 26279936);    // 1024 u32 epoch slots

  zero_cnt<<<4, 256, 0, stream>>>(arr);
  init2<<<128, 256, 0, stream>>>(h0, c0, seqX, cst);
  cast_x<<<8192, 256, 0, stream>>>(x, xb);
  bias_perm<<<64, 256, 0, stream>>>(bv[0], bv[1], bv[2], bv[3], bp);

  for (int l = 0; l < 4; ++l) {
    const int K = (l == 0) ? 512 : 1024;
    transpose_cast<true><<<dim3(128, 32), 256, 0, stream>>>(U[l], Utp, 1024, 4096);
    transpose_cast<true><<<dim3(128, K / 32), 256, 0, stream>>>(W[l], Wtp, K, 4096);
    const short* A = (l == 0) ? xb : seqX + 32768;
    gemm_bf16<1><<<dim3(32, 32), 256, 0, stream>>>(A, Wtp, bp + l * 4096, xWp,
                                                   4096, 4096, K);
    if (l) copy_h<<<64, 256, 0, stream>>>((const int*)(seqX + 128 * 32768),
                                          (int*)seqX);
    lstm_persist<<<PBLK, 256, 0, stream>>>(xWp, Utp, seqX, cst, arr, l * 128);
  }

  // dense head
  transpose_cast<false><<<dim3(32, 32), 256, 0, stream>>>(Wd1, Wtp, 1024, 1024);
  gemm_bf16<2><<<dim3(8, 32), 256, 0, stream>>>(seqX + 32768, Wtp, bd1, D1, 4096,
                                                1024, 1024);
  transpose_cast<false><<<dim3(16, 32), 256, 0, stream>>>(Wd2, Wtp, 1024, 512);
  gemm_bf16<3><<<dim3(4, 32), 256, 0, stream>>>(D1, Wtp, bd2, out, 4096, 512, 1024);

  finalize2<<<128, 256, 0, stream>>>(seqX + 128 * 32768, cst, out + 2097152);
}